// Round 8
// baseline (107.923 us; speedup 1.0000x reference)
//
#include <hip/hip_runtime.h>

#define NUM_HEADS 8
#define EMBED 64
#define BB 2
#define NN 512
#define TT 24

typedef _Float16 half4v __attribute__((ext_vector_type(4)));
typedef _Float16 half2v __attribute__((ext_vector_type(2)));
typedef _Float16 half8v __attribute__((ext_vector_type(8)));
typedef __fp16   fp16x2 __attribute__((ext_vector_type(2)));
typedef __fp16   fp16x4 __attribute__((ext_vector_type(4)));
typedef float    f32x4  __attribute__((ext_vector_type(4)));

#define KSTRIDE 20   // f16/row: 8 data + 8 zeros + 4 pad (40B, b64-aligned, conflict-free)
#define VSTRIDE 524  // f16/row for Vt (1048B; conflict-free lane spread)

// ---------------------------------------------------------------------------
// attn: fused QKV projection + node-axis attention via MFMA 16x16x16 f16.
// E^T = K·Q^T per 16x16 tile; C/D layout == B-operand layout, so P^T=exp(E^T)
// feeds O^T = V^T·P^T in registers. d=8 zero-padded to K=16. l via ones-row-8
// of Vt (O row 8 = softmax denom, free).
// R8: single kt loop with FOUR Q-frags / O-accums per wave (all 64 q rows):
// Kf/Vf loaded once per kt (LDS halved vs R7), 4 independent exp chains to
// saturate the trans pipe at 3 waves/SIMD.
// XCD-group swizzle: the 4 blocks sharing one (b,t,h-pair)'s 64B lines map to
// the same blockIdx%8 -> same XCD, concurrent -> each line fetched ~once.
// ---------------------------------------------------------------------------
__global__ __launch_bounds__(256) void attn_kernel(
    const float* __restrict__ values,
    const float* __restrict__ keys,
    const float* __restrict__ query,
    const float* __restrict__ Wv,
    const float* __restrict__ Wk,
    const float* __restrict__ Wq,
    float* __restrict__ out)
{
    __shared__ float w[192];                                   // Wq | Wk | Wv
    __shared__ __align__(16) _Float16 Kpad[NN * KSTRIDE];      // 20.0 KB
    __shared__ __align__(16) _Float16 Qpad[256 * KSTRIDE];     // 10.0 KB
    __shared__ __align__(16) _Float16 Vt[16 * VSTRIDE];        // 16.4 KB

    const int tid = threadIdx.x;
    // Bijective swizzle: w = (B%8)*96 + B/8; decode (b,t,h-pair,hlow,half).
    const int Bidx = blockIdx.x;
    const int wi   = ((Bidx & 7) * 96) + (Bidx >> 3);
    const int sub  = wi & 3;          // bit0: h low bit, bit1: q-half
    const int rest = wi >> 2;         // [0,192) = b*96 + t*4 + hpair
    const int half = sub >> 1;
    const int h    = ((rest & 3) << 1) | (sub & 1);
    const int t    = (rest >> 2) % TT;
    const int b    = rest / 96;

    // ---- Issue ALL global loads first (latency hidden under w/init/sync) ----
    const int r0 = 2 * tid;
    const long base0 = ((long)(b * NN + r0) * TT + t) * EMBED + h * 8;
    const long base1 = base0 + (long)TT * EMBED;
    const long qbase = ((long)(b * NN + half * 256 + tid) * TT + t) * EMBED + h * 8;
    float4 ka0 = *(const float4*)(keys + base0);
    float4 ka1 = *(const float4*)(keys + base0 + 4);
    float4 kb0 = *(const float4*)(keys + base1);
    float4 kb1 = *(const float4*)(keys + base1 + 4);
    float4 va0 = *(const float4*)(values + base0);
    float4 va1 = *(const float4*)(values + base0 + 4);
    float4 vb0 = *(const float4*)(values + base1);
    float4 vb1 = *(const float4*)(values + base1 + 4);
    float4 q0 = *(const float4*)(query + qbase);
    float4 q1 = *(const float4*)(query + qbase + 4);

    if (tid < 192) {
        float v;
        if (tid < 64)       v = Wq[tid];
        else if (tid < 128) v = Wk[tid - 64];
        else                v = Wv[tid - 128];
        w[tid] = v;
    }
    // Vt rows 8..15: row 8 = 1.0 (softmax-denominator trick), rows 9-15 = 0.
    {
        unsigned int* z = (unsigned int*)(Vt + 8 * VSTRIDE);
        for (int i = tid; i < 8 * VSTRIDE / 2; i += 256)
            z[i] = (i < VSTRIDE / 2) ? 0x3C003C00u : 0u;
    }
    __syncthreads();

    // ---- Projection + LDS staging ----
    {
        float k0[8] = {ka0.x, ka0.y, ka0.z, ka0.w, ka1.x, ka1.y, ka1.z, ka1.w};
        float k1[8] = {kb0.x, kb0.y, kb0.z, kb0.w, kb1.x, kb1.y, kb1.z, kb1.w};
        float v0[8] = {va0.x, va0.y, va0.z, va0.w, va1.x, va1.y, va1.z, va1.w};
        float v1[8] = {vb0.x, vb0.y, vb0.z, vb0.w, vb1.x, vb1.y, vb1.z, vb1.w};
        half4v klo0, khi0, klo1, khi1;
        #pragma unroll
        for (int dp = 0; dp < 8; ++dp) {
            float sk0 = 0.f, sk1 = 0.f, sv0 = 0.f, sv1 = 0.f;
            #pragma unroll
            for (int d = 0; d < 8; ++d) {
                const float wk = w[64 + dp * 8 + d], wvv = w[128 + dp * 8 + d];
                sk0 += k0[d] * wk;  sk1 += k1[d] * wk;
                sv0 += v0[d] * wvv; sv1 += v1[d] * wvv;
            }
            if (dp < 4) { klo0[dp] = (_Float16)sk0; klo1[dp] = (_Float16)sk1; }
            else        { khi0[dp - 4] = (_Float16)sk0; khi1[dp - 4] = (_Float16)sk1; }
            half2v vv = {(_Float16)sv0, (_Float16)sv1};
            *(half2v*)(Vt + dp * VSTRIDE + r0) = vv;
        }
        const half4v zz = {(_Float16)0.f, (_Float16)0.f, (_Float16)0.f, (_Float16)0.f};
        *(half4v*)(Kpad + r0 * KSTRIDE)            = klo0;
        *(half4v*)(Kpad + r0 * KSTRIDE + 4)        = khi0;
        *(half4v*)(Kpad + r0 * KSTRIDE + 8)        = zz;
        *(half4v*)(Kpad + r0 * KSTRIDE + 12)       = zz;
        *(half4v*)(Kpad + (r0 + 1) * KSTRIDE)      = klo1;
        *(half4v*)(Kpad + (r0 + 1) * KSTRIDE + 4)  = khi1;
        *(half4v*)(Kpad + (r0 + 1) * KSTRIDE + 8)  = zz;
        *(half4v*)(Kpad + (r0 + 1) * KSTRIDE + 12) = zz;

        float qx[8] = {q0.x, q0.y, q0.z, q0.w, q1.x, q1.y, q1.z, q1.w};
        const float scale = 0.125f * 1.44269504088896340736f; // /sqrt(64)*log2(e)
        half4v qlo, qhi;
        #pragma unroll
        for (int dp = 0; dp < 8; ++dp) {
            float s = 0.f;
            #pragma unroll
            for (int d = 0; d < 8; ++d) s += qx[d] * w[dp * 8 + d];
            s *= scale;
            if (dp < 4) qlo[dp] = (_Float16)s; else qhi[dp - 4] = (_Float16)s;
        }
        *(half4v*)(Qpad + tid * KSTRIDE)      = qlo;
        *(half4v*)(Qpad + tid * KSTRIDE + 4)  = qhi;
        *(half4v*)(Qpad + tid * KSTRIDE + 8)  = zz;
        *(half4v*)(Qpad + tid * KSTRIDE + 12) = zz;
    }
    __syncthreads();

    // ---- Main: wave owns 64 q rows; 4 Q-frags / O-accums; 32 k-tiles ----
    const int wv   = tid >> 6;
    const int lane = tid & 63;
    const int ln   = lane & 15;
    const int quad = lane >> 4;
    const f32x4 zero4 = {0.f, 0.f, 0.f, 0.f};

    const int ql0 = wv * 64;
    const half4v Qa = *(const half4v*)(Qpad + (ql0 +  0 + ln) * KSTRIDE + quad * 4);
    const half4v Qb = *(const half4v*)(Qpad + (ql0 + 16 + ln) * KSTRIDE + quad * 4);
    const half4v Qc = *(const half4v*)(Qpad + (ql0 + 32 + ln) * KSTRIDE + quad * 4);
    const half4v Qd = *(const half4v*)(Qpad + (ql0 + 48 + ln) * KSTRIDE + quad * 4);
    f32x4 Oa = {0.f, 0.f, 0.f, 0.f};
    f32x4 Ob = {0.f, 0.f, 0.f, 0.f};
    f32x4 Oc = {0.f, 0.f, 0.f, 0.f};
    f32x4 Od = {0.f, 0.f, 0.f, 0.f};

    #pragma unroll 2
    for (int kt = 0; kt < 32; ++kt) {
        half4v Kf = *(const half4v*)(Kpad + (kt * 16 + ln) * KSTRIDE + quad * 4);
        half4v Vf = *(const half4v*)(Vt + ln * VSTRIDE + kt * 16 + quad * 4);
        f32x4 Ea = __builtin_amdgcn_mfma_f32_16x16x16f16(Kf, Qa, zero4, 0, 0, 0);
        f32x4 Eb = __builtin_amdgcn_mfma_f32_16x16x16f16(Kf, Qb, zero4, 0, 0, 0);
        f32x4 Ec = __builtin_amdgcn_mfma_f32_16x16x16f16(Kf, Qc, zero4, 0, 0, 0);
        f32x4 Ed = __builtin_amdgcn_mfma_f32_16x16x16f16(Kf, Qd, zero4, 0, 0, 0);
        fp16x2 pa0 = __builtin_amdgcn_cvt_pkrtz(__builtin_amdgcn_exp2f(Ea[0]),
                                                __builtin_amdgcn_exp2f(Ea[1]));
        fp16x2 pa1 = __builtin_amdgcn_cvt_pkrtz(__builtin_amdgcn_exp2f(Ea[2]),
                                                __builtin_amdgcn_exp2f(Ea[3]));
        fp16x2 pb0 = __builtin_amdgcn_cvt_pkrtz(__builtin_amdgcn_exp2f(Eb[0]),
                                                __builtin_amdgcn_exp2f(Eb[1]));
        fp16x2 pb1 = __builtin_amdgcn_cvt_pkrtz(__builtin_amdgcn_exp2f(Eb[2]),
                                                __builtin_amdgcn_exp2f(Eb[3]));
        fp16x2 pc0 = __builtin_amdgcn_cvt_pkrtz(__builtin_amdgcn_exp2f(Ec[0]),
                                                __builtin_amdgcn_exp2f(Ec[1]));
        fp16x2 pc1 = __builtin_amdgcn_cvt_pkrtz(__builtin_amdgcn_exp2f(Ec[2]),
                                                __builtin_amdgcn_exp2f(Ec[3]));
        fp16x2 pd0 = __builtin_amdgcn_cvt_pkrtz(__builtin_amdgcn_exp2f(Ed[0]),
                                                __builtin_amdgcn_exp2f(Ed[1]));
        fp16x2 pd1 = __builtin_amdgcn_cvt_pkrtz(__builtin_amdgcn_exp2f(Ed[2]),
                                                __builtin_amdgcn_exp2f(Ed[3]));
        half4v Pa = __builtin_bit_cast(half4v, (fp16x4)__builtin_shufflevector(pa0, pa1, 0, 1, 2, 3));
        half4v Pb = __builtin_bit_cast(half4v, (fp16x4)__builtin_shufflevector(pb0, pb1, 0, 1, 2, 3));
        half4v Pc = __builtin_bit_cast(half4v, (fp16x4)__builtin_shufflevector(pc0, pc1, 0, 1, 2, 3));
        half4v Pd = __builtin_bit_cast(half4v, (fp16x4)__builtin_shufflevector(pd0, pd1, 0, 1, 2, 3));
        Oa = __builtin_amdgcn_mfma_f32_16x16x16f16(Vf, Pa, Oa, 0, 0, 0);
        Ob = __builtin_amdgcn_mfma_f32_16x16x16f16(Vf, Pb, Ob, 0, 0, 0);
        Oc = __builtin_amdgcn_mfma_f32_16x16x16f16(Vf, Pc, Oc, 0, 0, 0);
        Od = __builtin_amdgcn_mfma_f32_16x16x16f16(Vf, Pd, Od, 0, 0, 0);
    }

    // O row 8 (quad 2, reg 0) = softmax denominator per q-col.
    const float ia = 1.0f / __shfl(Oa[0], 32 + ln, 64);
    const float ib = 1.0f / __shfl(Ob[0], 32 + ln, 64);
    const float ic = 1.0f / __shfl(Oc[0], 32 + ln, 64);
    const float id = 1.0f / __shfl(Od[0], 32 + ln, 64);
    if (lane < 32) {  // quads 0,1 hold d=0..7
        const long rowa = (long)(b * NN + half * 256 + ql0 + ln);
        const long col  = h * 8 + quad * 4;
        const long oa = (rowa * TT + t) * EMBED + col;
        const long ob = ((rowa + 16) * TT + t) * EMBED + col;
        const long oc = ((rowa + 32) * TT + t) * EMBED + col;
        const long od = ((rowa + 48) * TT + t) * EMBED + col;
        *(float4*)(out + oa) = make_float4(Oa[0] * ia, Oa[1] * ia, Oa[2] * ia, Oa[3] * ia);
        *(float4*)(out + ob) = make_float4(Ob[0] * ib, Ob[1] * ib, Ob[2] * ib, Ob[3] * ib);
        *(float4*)(out + oc) = make_float4(Oc[0] * ic, Oc[1] * ic, Oc[2] * ic, Oc[3] * ic);
        *(float4*)(out + od) = make_float4(Od[0] * id, Od[1] * id, Od[2] * id, Od[3] * id);
    }
}

// ---------------------------------------------------------------------------
// proj: out = attn @ Wo^T + bo, in place — zero LDS, pure MFMA.
// Wave owns 16 rows x all 64 cols: 4 N-tiles of 16 cols, each K=64 via
// 2x mfma_f32_16x16x32_f16. A-frag loaded once up front (all io reads
// precede all io writes -> in-place safe, no barrier).
// ---------------------------------------------------------------------------
__global__ __launch_bounds__(256) void proj_kernel(
    const float* __restrict__ Wo,
    const float* __restrict__ bo,
    float* __restrict__ io)     // (24576, 64) in-place
{
    const int tid  = threadIdx.x;
    const int wv   = tid >> 6;
    const int lane = tid & 63;
    const int ln   = lane & 15;
    const int quad = lane >> 4;
    const int row0 = blockIdx.x * 64 + wv * 16;

    const float* arow = io + (long)(row0 + ln) * EMBED + quad * 8;
    float4 a0 = *(const float4*)(arow);
    float4 a1 = *(const float4*)(arow + 4);
    float4 a2 = *(const float4*)(arow + 32);
    float4 a3 = *(const float4*)(arow + 36);
    half8v Af1, Af2;
    Af1[0]=(_Float16)a0.x; Af1[1]=(_Float16)a0.y; Af1[2]=(_Float16)a0.z; Af1[3]=(_Float16)a0.w;
    Af1[4]=(_Float16)a1.x; Af1[5]=(_Float16)a1.y; Af1[6]=(_Float16)a1.z; Af1[7]=(_Float16)a1.w;
    Af2[0]=(_Float16)a2.x; Af2[1]=(_Float16)a2.y; Af2[2]=(_Float16)a2.z; Af2[3]=(_Float16)a2.w;
    Af2[4]=(_Float16)a3.x; Af2[5]=(_Float16)a3.y; Af2[6]=(_Float16)a3.z; Af2[7]=(_Float16)a3.w;

    #pragma unroll
    for (int nt = 0; nt < 4; ++nt) {
        const float* wrow = Wo + (long)(nt * 16 + ln) * EMBED + quad * 8;
        float4 w0 = *(const float4*)(wrow);
        float4 w1 = *(const float4*)(wrow + 4);
        float4 w2 = *(const float4*)(wrow + 32);
        float4 w3 = *(const float4*)(wrow + 36);
        half8v Bf1, Bf2;
        Bf1[0]=(_Float16)w0.x; Bf1[1]=(_Float16)w0.y; Bf1[2]=(_Float16)w0.z; Bf1[3]=(_Float16)w0.w;
        Bf1[4]=(_Float16)w1.x; Bf1[5]=(_Float16)w1.y; Bf1[6]=(_Float16)w1.z; Bf1[7]=(_Float16)w1.w;
        Bf2[0]=(_Float16)w2.x; Bf2[1]=(_Float16)w2.y; Bf2[2]=(_Float16)w2.z; Bf2[3]=(_Float16)w2.w;
        Bf2[4]=(_Float16)w3.x; Bf2[5]=(_Float16)w3.y; Bf2[6]=(_Float16)w3.z; Bf2[7]=(_Float16)w3.w;

        f32x4 D = {0.f, 0.f, 0.f, 0.f};
        D = __builtin_amdgcn_mfma_f32_16x16x32_f16(Af1, Bf1, D, 0, 0, 0);
        D = __builtin_amdgcn_mfma_f32_16x16x32_f16(Af2, Bf2, D, 0, 0, 0);

        const float bias = bo[nt * 16 + ln];
        #pragma unroll
        for (int r = 0; r < 4; ++r)
            io[(long)(row0 + quad * 4 + r) * EMBED + nt * 16 + ln] = D[r] + bias;
    }
}

extern "C" void kernel_launch(void* const* d_in, const int* in_sizes, int n_in,
                              void* d_out, int out_size, void* d_ws, size_t ws_size,
                              hipStream_t stream) {
    const float* values = (const float*)d_in[0];
    const float* keys   = (const float*)d_in[1];
    const float* query  = (const float*)d_in[2];
    const float* Wv     = (const float*)d_in[3];
    const float* Wk     = (const float*)d_in[4];
    const float* Wq     = (const float*)d_in[5];
    const float* Wo     = (const float*)d_in[6];
    const float* bo     = (const float*)d_in[7];
    float* out = (float*)d_out;

    (void)in_sizes; (void)n_in; (void)out_size; (void)d_ws; (void)ws_size;

    attn_kernel<<<BB * TT * NUM_HEADS * 2, 256, 0, stream>>>(
        values, keys, query, Wv, Wk, Wq, out);
    proj_kernel<<<(BB * NN * TT) / 64, 256, 0, stream>>>(Wo, bo, out);
}

// Round 10
// 105.423 us; speedup vs baseline: 1.0237x; 1.0237x over previous
//
#include <hip/hip_runtime.h>

#define NUM_HEADS 8
#define EMBED 64
#define BB 2
#define NN 512
#define TT 24

typedef _Float16 half4v __attribute__((ext_vector_type(4)));
typedef _Float16 half2v __attribute__((ext_vector_type(2)));
typedef _Float16 half8v __attribute__((ext_vector_type(8)));
typedef __fp16   fp16x2 __attribute__((ext_vector_type(2)));
typedef __fp16   fp16x4 __attribute__((ext_vector_type(4)));
typedef float    f32x4  __attribute__((ext_vector_type(4)));

#define KSTRIDE 20   // f16/row: 8 data + 8 zeros + 4 pad (40B, b64-aligned, conflict-free)
#define VSTRIDE 524  // f16/row for Vt (1048B; conflict-free lane spread)

// ---------------------------------------------------------------------------
// attn: fused QKV projection + node-axis attention via MFMA 16x16x16 f16
// (R7 structure, best measured). E^T = K·Q^T per 16x16 tile; C/D layout ==
// B-operand layout, so P^T=exp(E^T) feeds O^T = V^T·P^T in registers. d=8
// zero-padded to K=16. l via ones-row-8 of Vt (O row 8 = softmax denom).
// R10: output written as f16 to d_ws (3 MB) — same values proj's f32->f16
// cast produced before, so precision path is identical; halves the
// inter-kernel traffic.
// XCD-group swizzle: the 4 blocks sharing one (b,t,h-pair)'s 64B lines map
// to the same blockIdx%8 -> same XCD -> each line fetched from HBM ~once.
// ---------------------------------------------------------------------------
__global__ __launch_bounds__(256) void attn_kernel(
    const float* __restrict__ values,
    const float* __restrict__ keys,
    const float* __restrict__ query,
    const float* __restrict__ Wv,
    const float* __restrict__ Wk,
    const float* __restrict__ Wq,
    _Float16* __restrict__ ws)   // (B*N*T, 64) f16 pre-projection output
{
    __shared__ float w[192];                                   // Wq | Wk | Wv
    __shared__ __align__(16) _Float16 Kpad[NN * KSTRIDE];      // 20.0 KB
    __shared__ __align__(16) _Float16 Qpad[256 * KSTRIDE];     // 10.0 KB
    __shared__ __align__(16) _Float16 Vt[16 * VSTRIDE];        // 16.4 KB

    const int tid = threadIdx.x;
    // Bijective swizzle: wi = (B%8)*96 + B/8; decode (b,t,h-pair,hlow,half).
    const int Bidx = blockIdx.x;
    const int wi   = ((Bidx & 7) * 96) + (Bidx >> 3);
    const int sub  = wi & 3;          // bit0: h low bit, bit1: q-half
    const int rest = wi >> 2;         // [0,192) = b*96 + t*4 + hpair
    const int half = sub >> 1;
    const int h    = ((rest & 3) << 1) | (sub & 1);
    const int t    = (rest >> 2) % TT;
    const int b    = rest / 96;

    // ---- Issue ALL global loads first (latency hidden under w/init/sync) ----
    const int r0 = 2 * tid;
    const long base0 = ((long)(b * NN + r0) * TT + t) * EMBED + h * 8;
    const long base1 = base0 + (long)TT * EMBED;
    const long qbase = ((long)(b * NN + half * 256 + tid) * TT + t) * EMBED + h * 8;
    float4 ka0 = *(const float4*)(keys + base0);
    float4 ka1 = *(const float4*)(keys + base0 + 4);
    float4 kb0 = *(const float4*)(keys + base1);
    float4 kb1 = *(const float4*)(keys + base1 + 4);
    float4 va0 = *(const float4*)(values + base0);
    float4 va1 = *(const float4*)(values + base0 + 4);
    float4 vb0 = *(const float4*)(values + base1);
    float4 vb1 = *(const float4*)(values + base1 + 4);
    float4 q0 = *(const float4*)(query + qbase);
    float4 q1 = *(const float4*)(query + qbase + 4);

    if (tid < 192) {
        float v;
        if (tid < 64)       v = Wq[tid];
        else if (tid < 128) v = Wk[tid - 64];
        else                v = Wv[tid - 128];
        w[tid] = v;
    }
    // Vt rows 8..15: row 8 = 1.0 (softmax-denominator trick), rows 9-15 = 0.
    {
        unsigned int* z = (unsigned int*)(Vt + 8 * VSTRIDE);
        for (int i = tid; i < 8 * VSTRIDE / 2; i += 256)
            z[i] = (i < VSTRIDE / 2) ? 0x3C003C00u : 0u;
    }
    __syncthreads();

    // ---- Projection + LDS staging ----
    {
        float k0[8] = {ka0.x, ka0.y, ka0.z, ka0.w, ka1.x, ka1.y, ka1.z, ka1.w};
        float k1[8] = {kb0.x, kb0.y, kb0.z, kb0.w, kb1.x, kb1.y, kb1.z, kb1.w};
        float v0[8] = {va0.x, va0.y, va0.z, va0.w, va1.x, va1.y, va1.z, va1.w};
        float v1[8] = {vb0.x, vb0.y, vb0.z, vb0.w, vb1.x, vb1.y, vb1.z, vb1.w};
        half4v klo0, khi0, klo1, khi1;
        #pragma unroll
        for (int dp = 0; dp < 8; ++dp) {
            float sk0 = 0.f, sk1 = 0.f, sv0 = 0.f, sv1 = 0.f;
            #pragma unroll
            for (int d = 0; d < 8; ++d) {
                const float wk = w[64 + dp * 8 + d], wvv = w[128 + dp * 8 + d];
                sk0 += k0[d] * wk;  sk1 += k1[d] * wk;
                sv0 += v0[d] * wvv; sv1 += v1[d] * wvv;
            }
            if (dp < 4) { klo0[dp] = (_Float16)sk0; klo1[dp] = (_Float16)sk1; }
            else        { khi0[dp - 4] = (_Float16)sk0; khi1[dp - 4] = (_Float16)sk1; }
            half2v vv = {(_Float16)sv0, (_Float16)sv1};
            *(half2v*)(Vt + dp * VSTRIDE + r0) = vv;
        }
        const half4v zz = {(_Float16)0.f, (_Float16)0.f, (_Float16)0.f, (_Float16)0.f};
        *(half4v*)(Kpad + r0 * KSTRIDE)            = klo0;
        *(half4v*)(Kpad + r0 * KSTRIDE + 4)        = khi0;
        *(half4v*)(Kpad + r0 * KSTRIDE + 8)        = zz;
        *(half4v*)(Kpad + r0 * KSTRIDE + 12)       = zz;
        *(half4v*)(Kpad + (r0 + 1) * KSTRIDE)      = klo1;
        *(half4v*)(Kpad + (r0 + 1) * KSTRIDE + 4)  = khi1;
        *(half4v*)(Kpad + (r0 + 1) * KSTRIDE + 8)  = zz;
        *(half4v*)(Kpad + (r0 + 1) * KSTRIDE + 12) = zz;

        float qx[8] = {q0.x, q0.y, q0.z, q0.w, q1.x, q1.y, q1.z, q1.w};
        const float scale = 0.125f * 1.44269504088896340736f; // /sqrt(64)*log2(e)
        half4v qlo, qhi;
        #pragma unroll
        for (int dp = 0; dp < 8; ++dp) {
            float s = 0.f;
            #pragma unroll
            for (int d = 0; d < 8; ++d) s += qx[d] * w[dp * 8 + d];
            s *= scale;
            if (dp < 4) qlo[dp] = (_Float16)s; else qhi[dp - 4] = (_Float16)s;
        }
        *(half4v*)(Qpad + tid * KSTRIDE)      = qlo;
        *(half4v*)(Qpad + tid * KSTRIDE + 4)  = qhi;
        *(half4v*)(Qpad + tid * KSTRIDE + 8)  = zz;
        *(half4v*)(Qpad + tid * KSTRIDE + 12) = zz;
    }
    __syncthreads();

    // ---- Main: wave owns 32 q per pass, 2 passes, 32 k-tiles of 16 nodes ----
    const int wv   = tid >> 6;
    const int lane = tid & 63;
    const int ln   = lane & 15;
    const int quad = lane >> 4;
    const f32x4 zero4 = {0.f, 0.f, 0.f, 0.f};

    #pragma unroll 1
    for (int pass = 0; pass < 2; ++pass) {
        const int ql0 = pass * 128 + wv * 32;
        const half4v Qa = *(const half4v*)(Qpad + (ql0 + ln) * KSTRIDE + quad * 4);
        const half4v Qb = *(const half4v*)(Qpad + (ql0 + 16 + ln) * KSTRIDE + quad * 4);
        f32x4 Oa = {0.f, 0.f, 0.f, 0.f};
        f32x4 Ob = {0.f, 0.f, 0.f, 0.f};
        #pragma unroll 4
        for (int kt = 0; kt < 32; ++kt) {
            half4v Kf = *(const half4v*)(Kpad + (kt * 16 + ln) * KSTRIDE + quad * 4);
            half4v Vf = *(const half4v*)(Vt + ln * VSTRIDE + kt * 16 + quad * 4);
            f32x4 Ea = __builtin_amdgcn_mfma_f32_16x16x16f16(Kf, Qa, zero4, 0, 0, 0);
            f32x4 Eb = __builtin_amdgcn_mfma_f32_16x16x16f16(Kf, Qb, zero4, 0, 0, 0);
            fp16x2 pa0 = __builtin_amdgcn_cvt_pkrtz(__builtin_amdgcn_exp2f(Ea[0]),
                                                    __builtin_amdgcn_exp2f(Ea[1]));
            fp16x2 pa1 = __builtin_amdgcn_cvt_pkrtz(__builtin_amdgcn_exp2f(Ea[2]),
                                                    __builtin_amdgcn_exp2f(Ea[3]));
            fp16x2 pb0 = __builtin_amdgcn_cvt_pkrtz(__builtin_amdgcn_exp2f(Eb[0]),
                                                    __builtin_amdgcn_exp2f(Eb[1]));
            fp16x2 pb1 = __builtin_amdgcn_cvt_pkrtz(__builtin_amdgcn_exp2f(Eb[2]),
                                                    __builtin_amdgcn_exp2f(Eb[3]));
            half4v Pa = __builtin_bit_cast(half4v,
                (fp16x4)__builtin_shufflevector(pa0, pa1, 0, 1, 2, 3));
            half4v Pb = __builtin_bit_cast(half4v,
                (fp16x4)__builtin_shufflevector(pb0, pb1, 0, 1, 2, 3));
            Oa = __builtin_amdgcn_mfma_f32_16x16x16f16(Vf, Pa, Oa, 0, 0, 0);
            Ob = __builtin_amdgcn_mfma_f32_16x16x16f16(Vf, Pb, Ob, 0, 0, 0);
        }
        // O row 8 (quad 2, reg 0) = softmax denominator per q-col.
        const float la = __shfl(Oa[0], 32 + ln, 64);
        const float lb = __shfl(Ob[0], 32 + ln, 64);
        const float ia = 1.0f / la;
        const float ib = 1.0f / lb;
        if (lane < 32) {  // quads 0,1 hold d=0..7
            const long oa = ((long)(b * NN + half * 256 + ql0 + ln) * TT + t) * EMBED
                          + h * 8 + quad * 4;
            const long ob = ((long)(b * NN + half * 256 + ql0 + 16 + ln) * TT + t) * EMBED
                          + h * 8 + quad * 4;
            fp16x2 oa0 = __builtin_amdgcn_cvt_pkrtz(Oa[0] * ia, Oa[1] * ia);
            fp16x2 oa1 = __builtin_amdgcn_cvt_pkrtz(Oa[2] * ia, Oa[3] * ia);
            fp16x2 ob0 = __builtin_amdgcn_cvt_pkrtz(Ob[0] * ib, Ob[1] * ib);
            fp16x2 ob1 = __builtin_amdgcn_cvt_pkrtz(Ob[2] * ib, Ob[3] * ib);
            *(fp16x4*)(ws + oa) = __builtin_shufflevector(oa0, oa1, 0, 1, 2, 3);
            *(fp16x4*)(ws + ob) = __builtin_shufflevector(ob0, ob1, 0, 1, 2, 3);
        }
    }
}

// ---------------------------------------------------------------------------
// proj: out = ws @ Wo^T + bo — zero LDS, pure MFMA, f16 input from ws.
// Wave owns 16 rows x all 64 cols: 4 N-tiles of 16 cols, each K=64 via
// 2x mfma_f32_16x16x32_f16. A-frags are direct 16B f16 loads from ws.
// ---------------------------------------------------------------------------
__global__ __launch_bounds__(256) void proj_kernel(
    const float* __restrict__ Wo,
    const float* __restrict__ bo,
    const _Float16* __restrict__ ws,  // (24576, 64) f16
    float* __restrict__ out)          // (24576, 64) f32
{
    const int tid  = threadIdx.x;
    const int wv   = tid >> 6;
    const int lane = tid & 63;
    const int ln   = lane & 15;
    const int quad = lane >> 4;
    const int row0 = blockIdx.x * 64 + wv * 16;

    // A-frag: A[m=ln][k=quad*8+j] and [32+quad*8+j] — contiguous 16B each.
    const _Float16* arow = ws + (long)(row0 + ln) * EMBED + quad * 8;
    half8v Af1 = *(const half8v*)(arow);
    half8v Af2 = *(const half8v*)(arow + 32);

    #pragma unroll
    for (int nt = 0; nt < 4; ++nt) {
        const float* wrow = Wo + (long)(nt * 16 + ln) * EMBED + quad * 8;
        float4 w0 = *(const float4*)(wrow);
        float4 w1 = *(const float4*)(wrow + 4);
        float4 w2 = *(const float4*)(wrow + 32);
        float4 w3 = *(const float4*)(wrow + 36);
        half8v Bf1, Bf2;
        Bf1[0]=(_Float16)w0.x; Bf1[1]=(_Float16)w0.y; Bf1[2]=(_Float16)w0.z; Bf1[3]=(_Float16)w0.w;
        Bf1[4]=(_Float16)w1.x; Bf1[5]=(_Float16)w1.y; Bf1[6]=(_Float16)w1.z; Bf1[7]=(_Float16)w1.w;
        Bf2[0]=(_Float16)w2.x; Bf2[1]=(_Float16)w2.y; Bf2[2]=(_Float16)w2.z; Bf2[3]=(_Float16)w2.w;
        Bf2[4]=(_Float16)w3.x; Bf2[5]=(_Float16)w3.y; Bf2[6]=(_Float16)w3.z; Bf2[7]=(_Float16)w3.w;

        f32x4 D = {0.f, 0.f, 0.f, 0.f};
        D = __builtin_amdgcn_mfma_f32_16x16x32_f16(Af1, Bf1, D, 0, 0, 0);
        D = __builtin_amdgcn_mfma_f32_16x16x32_f16(Af2, Bf2, D, 0, 0, 0);

        const float bias = bo[nt * 16 + ln];
        #pragma unroll
        for (int r = 0; r < 4; ++r)
            out[(long)(row0 + quad * 4 + r) * EMBED + nt * 16 + ln] = D[r] + bias;
    }
}

extern "C" void kernel_launch(void* const* d_in, const int* in_sizes, int n_in,
                              void* d_out, int out_size, void* d_ws, size_t ws_size,
                              hipStream_t stream) {
    const float* values = (const float*)d_in[0];
    const float* keys   = (const float*)d_in[1];
    const float* query  = (const float*)d_in[2];
    const float* Wv     = (const float*)d_in[3];
    const float* Wk     = (const float*)d_in[4];
    const float* Wq     = (const float*)d_in[5];
    const float* Wo     = (const float*)d_in[6];
    const float* bo     = (const float*)d_in[7];
    float* out = (float*)d_out;
    _Float16* ws = (_Float16*)d_ws;   // 3 MB used of ws_size

    (void)in_sizes; (void)n_in; (void)out_size; (void)ws_size;

    attn_kernel<<<BB * TT * NUM_HEADS * 2, 256, 0, stream>>>(
        values, keys, query, Wv, Wk, Wq, ws);
    proj_kernel<<<(BB * NN * TT) / 64, 256, 0, stream>>>(Wo, bo, ws, out);
}